// Round 4
// baseline (182.631 us; speedup 1.0000x reference)
//
#include <hip/hip_runtime.h>
#include <hip/hip_bf16.h>

// NAM_89739046683406: per-feature tiny MLP (B=32768, F=128, H=64)
// logit(b) = bias + sum_f [ relu(relu(x[b,f]*w1[f]+b1[f]) @ w2[f] + b2[f]) . w3[f] + b3[f] ]
// out = [1-sigmoid, sigmoid]
//
// R2 structure (second resubmit after broker-infra failures): pre-pass converts
// w2 -> bf16 in MFMA A-fragment order (ws, 1MB) and x -> bf16 transposed
// xT[f][b] (ws, 8.4MB). Main kernel: no LDS, no syncs, swapped-operand MFMA
// (D[g][b]) so the contrib reduction is a 2-step quad butterfly; atomicAdd into
// a 128KB logit buffer; tiny final sigmoid kernel.

#define B_SZ 32768
#define F_SZ 128
#define H_SZ 64
#define BM   128      // batch rows per block (4 waves x 32 rows)

typedef __attribute__((ext_vector_type(8))) short short8;   // bf16 x8 (4 VGPRs)
typedef __attribute__((ext_vector_type(4))) float floatx4;  // fp32 x4 acc

// round-half-up bf16 (== RNE except exact ties; inputs are generic floats)
__device__ __forceinline__ unsigned short f2bf(float f) {
    return (unsigned short)((__float_as_uint(f) + 0x8000u) >> 16);
}
__device__ __forceinline__ unsigned pkbf(float a, float b) {
    unsigned ua = __float_as_uint(a) + 0x8000u;
    unsigned ub = __float_as_uint(b) + 0x8000u;
    return (ua >> 16) | (ub & 0xFFFF0000u);
}

// ws layout (bytes):
//   [0, 1MB)          w2bf: per f, 8 chunks x 64 lanes x short8 (A-fragment order)
//   [1MB, 1.125MB)    logit: B_SZ floats
//   [1.125MB, ~9.5MB) xT: F_SZ x B_SZ bf16 (ushort)
#define WS_W2   0
#define WS_LOG  (1024 * 1024)
#define WS_XT   (WS_LOG + B_SZ * 4)

// ---- pre-pass: w2 fp32 -> bf16, swizzled to A-fragment order ----
// chunk c = gt*2+ks; lane; elem j: value = w2[f][k=ks*32+(lane>>4)*8+j][g=gt*16+(lane&15)]
__global__ __launch_bounds__(256)
void nam_prep_w2(const float* __restrict__ w2, unsigned short* __restrict__ w2bf)
{
    const int f = blockIdx.x;
    const float* w2f = w2 + (size_t)f * H_SZ * H_SZ;
    #pragma unroll
    for (int it = 0; it < 2; ++it) {
        int idx  = it * 256 + threadIdx.x;   // 0..511
        int c    = idx >> 6;                 // 0..7
        int lane = idx & 63;
        int g    = (c >> 1) * 16 + (lane & 15);
        int k0   = (c & 1) * 32 + (lane >> 4) * 8;
        union { short8 s; unsigned u[4]; } o;
        #pragma unroll
        for (int jj = 0; jj < 4; ++jj) {
            float a = w2f[(k0 + 2 * jj)     * H_SZ + g];
            float b = w2f[(k0 + 2 * jj + 1) * H_SZ + g];
            o.u[jj] = pkbf(a, b);
        }
        *(short8*)(w2bf + (size_t)f * 4096 + idx * 8) = o.s;
    }
}

// ---- pre-pass: x (B,F) fp32 -> xT (F,B) bf16, LDS tile transpose ----
__global__ __launch_bounds__(256)
void nam_xt(const float* __restrict__ x, unsigned short* __restrict__ xT)
{
    __shared__ float t[32][33];
    const int bB = blockIdx.x;        // batch tile (32 rows)
    const int bF = blockIdx.y;        // feature tile (32 cols)
    const int tx = threadIdx.x & 31, ty = threadIdx.x >> 5;   // ty 0..7
    #pragma unroll
    for (int i = 0; i < 4; ++i)
        t[ty + 8 * i][tx] = x[(size_t)(bB * 32 + ty + 8 * i) * F_SZ + bF * 32 + tx];
    __syncthreads();
    #pragma unroll
    for (int i = 0; i < 4; ++i)
        xT[(size_t)(bF * 32 + ty + 8 * i) * B_SZ + bB * 32 + tx] = f2bf(t[tx][ty + 8 * i]);
}

__global__ __launch_bounds__(256)
void nam_zero(float* __restrict__ p)
{
    p[blockIdx.x * 256 + threadIdx.x] = 0.0f;
}

// ---- main: one block = 1 feature x 128 batch rows; no LDS ----
__global__ __launch_bounds__(256)
void nam_main(const unsigned short* __restrict__ xT,
              const float* __restrict__ w1, const float* __restrict__ b1,
              const float* __restrict__ b2, const float* __restrict__ w3,
              const float* __restrict__ b3,
              const unsigned short* __restrict__ w2bf,
              float* __restrict__ logit)
{
    const int f    = blockIdx.x >> 8;          // feature (f-major: concurrent
    const int rg   = blockIdx.x & 255;         //  blocks spread across rows)
    const int r0   = rg * BM;
    const int tid  = threadIdx.x;
    const int lane = tid & 63;
    const int wv   = tid >> 6;                 // wave -> rows [wv*32, wv*32+32)
    const int l15  = lane & 15;
    const int quad = lane >> 4;

    // w2 A-fragments: 8 coalesced 16B loads, L2-resident (1MB total)
    const short8* wp = (const short8*)(w2bf + (size_t)f * 4096);
    short8 wfrag[4][2];
    #pragma unroll
    for (int gt = 0; gt < 4; ++gt)
        #pragma unroll
        for (int ks = 0; ks < 2; ++ks)
            wfrag[gt][ks] = wp[(gt * 2 + ks) * 64 + lane];

    // x loads: coalesced bf16 from xT
    float xv[2];
    #pragma unroll
    for (int bt = 0; bt < 2; ++bt) {
        unsigned short u = xT[(size_t)f * B_SZ + r0 + wv * 32 + bt * 16 + l15];
        xv[bt] = __uint_as_float(((unsigned)u) << 16);
    }

    // layer 1 -> h1 B-fragments: B[k=quad*8+j][n=l15], batch n = bt*16+l15
    short8 hfrag[2][2];
    #pragma unroll
    for (int ks = 0; ks < 2; ++ks) {
        const float4* w1p = (const float4*)(w1 + f * H_SZ + ks * 32 + quad * 8);
        const float4* b1p = (const float4*)(b1 + f * H_SZ + ks * 32 + quad * 8);
        float wk[8], bk[8];
        *(float4*)&wk[0] = w1p[0]; *(float4*)&wk[4] = w1p[1];
        *(float4*)&bk[0] = b1p[0]; *(float4*)&bk[4] = b1p[1];
        #pragma unroll
        for (int bt = 0; bt < 2; ++bt) {
            union { short8 s; unsigned u[4]; } o;
            #pragma unroll
            for (int jj = 0; jj < 4; ++jj) {
                float h0 = fmaxf(fmaf(xv[bt], wk[2 * jj],     bk[2 * jj]),     0.0f);
                float h1 = fmaxf(fmaf(xv[bt], wk[2 * jj + 1], bk[2 * jj + 1]), 0.0f);
                o.u[jj] = pkbf(h0, h1);
            }
            hfrag[bt][ks] = o.s;
        }
    }

    // MFMA: D[g][b] = sum_h w2[h][g] * h1[b][h]
    floatx4 acc[4][2];
    #pragma unroll
    for (int gt = 0; gt < 4; ++gt)
        #pragma unroll
        for (int bt = 0; bt < 2; ++bt)
            acc[gt][bt] = (floatx4)(0.0f);
    #pragma unroll
    for (int ks = 0; ks < 2; ++ks)
        #pragma unroll
        for (int gt = 0; gt < 4; ++gt)
            #pragma unroll
            for (int bt = 0; bt < 2; ++bt)
                acc[gt][bt] = __builtin_amdgcn_mfma_f32_16x16x32_bf16(
                    wfrag[gt][ks], hfrag[bt][ks], acc[gt][bt], 0, 0, 0);

    // epilogue: +b2, relu, .w3 ; D layout: g = gt*16+quad*4+i, b = bt*16+l15
    float s[2] = {0.0f, 0.0f};
    #pragma unroll
    for (int gt = 0; gt < 4; ++gt) {
        float4 b2v = *(const float4*)(b2 + f * H_SZ + gt * 16 + quad * 4);
        float4 w3v = *(const float4*)(w3 + f * H_SZ + gt * 16 + quad * 4);
        float b2a[4] = {b2v.x, b2v.y, b2v.z, b2v.w};
        float w3a[4] = {w3v.x, w3v.y, w3v.z, w3v.w};
        #pragma unroll
        for (int bt = 0; bt < 2; ++bt)
            #pragma unroll
            for (int i = 0; i < 4; ++i)
                s[bt] = fmaf(fmaxf(acc[gt][bt][i] + b2a[i], 0.0f), w3a[i], s[bt]);
    }
    // reduce across quads (lanes l15 equal, quad differs): 2 butterfly steps
    #pragma unroll
    for (int bt = 0; bt < 2; ++bt) {
        s[bt] += __shfl_xor(s[bt], 16, 64);
        s[bt] += __shfl_xor(s[bt], 32, 64);
    }
    if (quad == 0) {
        float b3c = b3[f];
        #pragma unroll
        for (int bt = 0; bt < 2; ++bt)
            atomicAdd(&logit[r0 + wv * 32 + bt * 16 + l15], s[bt] + b3c);
    }
}

__global__ __launch_bounds__(256)
void nam_final(const float* __restrict__ logit, const float* __restrict__ bias,
               float* __restrict__ out)
{
    int b = blockIdx.x * 256 + threadIdx.x;
    float s = logit[b] + bias[0];
    float p = 1.0f / (1.0f + __expf(-s));
    ((float2*)out)[b] = make_float2(1.0f - p, p);
}

extern "C" void kernel_launch(void* const* d_in, const int* in_sizes, int n_in,
                              void* d_out, int out_size, void* d_ws, size_t ws_size,
                              hipStream_t stream)
{
    const float* x    = (const float*)d_in[0];
    const float* w1   = (const float*)d_in[1];
    const float* b1   = (const float*)d_in[2];
    const float* w2   = (const float*)d_in[3];
    const float* b2   = (const float*)d_in[4];
    const float* w3   = (const float*)d_in[5];
    const float* b3   = (const float*)d_in[6];
    const float* bias = (const float*)d_in[7];
    float* out = (float*)d_out;

    unsigned short* w2bf  = (unsigned short*)((char*)d_ws + WS_W2);
    float*          logit = (float*)((char*)d_ws + WS_LOG);
    unsigned short* xT    = (unsigned short*)((char*)d_ws + WS_XT);

    nam_prep_w2<<<dim3(F_SZ), dim3(256), 0, stream>>>(w2, w2bf);
    nam_xt<<<dim3(B_SZ / 32, F_SZ / 32), dim3(256), 0, stream>>>(x, xT);
    nam_zero<<<dim3(B_SZ / 256), dim3(256), 0, stream>>>(logit);
    nam_main<<<dim3((B_SZ / BM) * F_SZ), dim3(256), 0, stream>>>(
        xT, w1, b1, b2, w3, b3, w2bf, logit);
    nam_final<<<dim3(B_SZ / 256), dim3(256), 0, stream>>>(logit, bias, out);
}